// Round 1
// baseline (2218.254 us; speedup 1.0000x reference)
//
#include <hip/hip_runtime.h>
#include <math.h>

// Problem constants (fixed by the reference setup_inputs)
#define BATCH 32
#define CH    192
#define TFEAT 2048
#define TTXT  512
#define NEGINF (-1e9f)

#define ATTN_ELEMS ((size_t)BATCH * TFEAT * TTXT)   // 33,554,432
#define DUR_OFF    ATTN_ELEMS
#define NEG_OFF    (ATTN_ELEMS + (size_t)BATCH * TTXT)

// ---------------------------------------------------------------------------
// Kernel A: cadd[b][s] = neg1 + neg4 = sum_c(-0.5*log(2pi) - logs)
//                        + sum_c(-0.5*m^2*exp(-2*logs))
// ---------------------------------------------------------------------------
__global__ void k_cadd(const float* __restrict__ m_p,
                       const float* __restrict__ logs_p,
                       float* __restrict__ cadd) {
  int gid = blockIdx.x * 256 + threadIdx.x;        // 0 .. 16383
  int b = gid >> 9, s = gid & (TTXT - 1);
  const float* mp = m_p    + (size_t)b * CH * TTXT + s;
  const float* lp = logs_p + (size_t)b * CH * TTXT + s;
  float acc = -0.5f * 1.8378770664093453f * (float)CH;   // -C/2 * log(2*pi)
  #pragma unroll 4
  for (int c = 0; c < CH; ++c) {
    float l = lp[(size_t)c * TTXT];
    float m = mp[(size_t)c * TTXT];
    float r = __expf(-2.0f * l);
    acc -= l + 0.5f * m * m * r;
  }
  cadd[gid] = acc;
}

// ---------------------------------------------------------------------------
// Kernel B: neg[b,t,s] = sum_c z[b,c,t]*(W1[c,s] + z[b,c,t]*W2[c,s]) + cadd[b,s]
//   W1 = m_p * exp(-2*logs), W2 = -0.5 * exp(-2*logs), built on the fly.
// fp32 vector GEMM (no fp32 MFMA on CDNA4). TN layout: K is the slow dim of
// both operands -> coalesced tile loads.
// ---------------------------------------------------------------------------
#define BM 128
#define BN 128
#define BK 16

__device__ __forceinline__ void mkw(float m, float l, float& w1, float& w2) {
  float r = __expf(-2.0f * l);
  w1 = m * r;
  w2 = -0.5f * r;
}

__global__ __launch_bounds__(256, 2)
void k_gemm(const float* __restrict__ z_p, const float* __restrict__ m_p,
            const float* __restrict__ logs_p, const float* __restrict__ cadd,
            float* __restrict__ neg) {
  __shared__ float Az[BK][BM];
  __shared__ float W1[BK][BN];
  __shared__ float W2[BK][BN];

  int blk = blockIdx.x;
  int sb = blk & 3;            // TTXT/BN = 4
  int tb = (blk >> 2) & 15;    // TFEAT/BM = 16
  int b  = blk >> 6;
  int tid = threadIdx.x;
  int tx = tid & 15, ty = tid >> 4;

  const float* zb = z_p    + (size_t)b * CH * TFEAT + (size_t)tb * BM;
  const float* mb = m_p    + (size_t)b * CH * TTXT  + (size_t)sb * BN;
  const float* lb = logs_p + (size_t)b * CH * TTXT  + (size_t)sb * BN;

  int r0 = tid >> 5;           // 0..7 (staging row; also row+8)
  int c4 = tid & 31;           // 0..31 (float4 column)

  float acc[8][8];
  #pragma unroll
  for (int i = 0; i < 8; ++i)
    #pragma unroll
    for (int j = 0; j < 8; ++j) acc[i][j] = 0.0f;

  for (int ko = 0; ko < CH / BK; ++ko) {
    // global -> regs (coalesced float4)
    float4 za  = *(const float4*)(zb + (size_t)(ko * BK + r0    ) * TFEAT + c4 * 4);
    float4 zb4 = *(const float4*)(zb + (size_t)(ko * BK + r0 + 8) * TFEAT + c4 * 4);
    float4 ma  = *(const float4*)(mb + (size_t)(ko * BK + r0    ) * TTXT  + c4 * 4);
    float4 mb4 = *(const float4*)(mb + (size_t)(ko * BK + r0 + 8) * TTXT  + c4 * 4);
    float4 la  = *(const float4*)(lb + (size_t)(ko * BK + r0    ) * TTXT  + c4 * 4);
    float4 lb4 = *(const float4*)(lb + (size_t)(ko * BK + r0 + 8) * TTXT  + c4 * 4);

    float4 w1a, w2a, w1b, w2b;
    mkw(ma.x, la.x, w1a.x, w2a.x);  mkw(ma.y, la.y, w1a.y, w2a.y);
    mkw(ma.z, la.z, w1a.z, w2a.z);  mkw(ma.w, la.w, w1a.w, w2a.w);
    mkw(mb4.x, lb4.x, w1b.x, w2b.x); mkw(mb4.y, lb4.y, w1b.y, w2b.y);
    mkw(mb4.z, lb4.z, w1b.z, w2b.z); mkw(mb4.w, lb4.w, w1b.w, w2b.w);

    __syncthreads();   // previous tile fully consumed
    *(float4*)&Az[r0    ][c4 * 4] = za;
    *(float4*)&Az[r0 + 8][c4 * 4] = zb4;
    *(float4*)&W1[r0    ][c4 * 4] = w1a;
    *(float4*)&W1[r0 + 8][c4 * 4] = w1b;
    *(float4*)&W2[r0    ][c4 * 4] = w2a;
    *(float4*)&W2[r0 + 8][c4 * 4] = w2b;
    __syncthreads();

    #pragma unroll
    for (int kk = 0; kk < BK; ++kk) {
      float4 a0 = *(const float4*)&Az[kk][ty * 8];
      float4 a1 = *(const float4*)&Az[kk][ty * 8 + 4];
      float4 p0 = *(const float4*)&W1[kk][tx * 8];
      float4 p1 = *(const float4*)&W1[kk][tx * 8 + 4];
      float4 q0 = *(const float4*)&W2[kk][tx * 8];
      float4 q1 = *(const float4*)&W2[kk][tx * 8 + 4];
      float a[8]  = {a0.x, a0.y, a0.z, a0.w, a1.x, a1.y, a1.z, a1.w};
      float w1v[8] = {p0.x, p0.y, p0.z, p0.w, p1.x, p1.y, p1.z, p1.w};
      float w2v[8] = {q0.x, q0.y, q0.z, q0.w, q1.x, q1.y, q1.z, q1.w};
      #pragma unroll
      for (int i = 0; i < 8; ++i)
        #pragma unroll
        for (int j = 0; j < 8; ++j)
          acc[i][j] = fmaf(a[i], fmaf(a[i], w2v[j], w1v[j]), acc[i][j]);
    }
  }

  // epilogue: + cadd, store
  const float* cb = cadd + b * TTXT + sb * BN + tx * 8;
  float c0[8];
  #pragma unroll
  for (int j = 0; j < 8; ++j) c0[j] = cb[j];
  float* ob = neg + (size_t)b * TFEAT * TTXT + (size_t)(tb * BM) * TTXT + sb * BN + tx * 8;
  #pragma unroll
  for (int i = 0; i < 8; ++i) {
    float4 o0 = {acc[i][0] + c0[0], acc[i][1] + c0[1], acc[i][2] + c0[2], acc[i][3] + c0[3]};
    float4 o1 = {acc[i][4] + c0[4], acc[i][5] + c0[5], acc[i][6] + c0[6], acc[i][7] + c0[7]};
    float* row = ob + (size_t)(ty * 8 + i) * TTXT;
    *(float4*)(row)     = o0;
    *(float4*)(row + 4) = o1;
  }
}

// ---------------------------------------------------------------------------
// Kernel C: forward DP + decision bits in LDS + serial backtrack.
// One wave (64 lanes) per batch element, x = 8*lane + j, prev row in regs.
// bit(y,x) = (x!=0) & ((x==y) | (prev[x] < prev[x-1]))  [prev = values[y-1]]
// Packed 4 rows per u32: bits[y>>2][x>>3], bit position (y&3)*8 + (x&7).
// ---------------------------------------------------------------------------
__global__ __launch_bounds__(64)
void k_dp(const float* __restrict__ neg, float* __restrict__ dur,
          int* __restrict__ idx_out, const float* __restrict__ x_mask) {
  __shared__ unsigned int bits[TFEAT / 4][64];   // 128 KiB
  int b = blockIdx.x;
  int lane = threadIdx.x;
  const float* nb = neg + (size_t)b * TFEAT * TTXT + lane * 8;

  float prev[8];
  #pragma unroll
  for (int j = 0; j < 8; ++j) prev[j] = NEGINF;

  unsigned int packed = 0;
  float4 pf0 = *(const float4*)(nb);
  float4 pf1 = *(const float4*)(nb + 4);
  int xbase = lane << 3;

  for (int y = 0; y < TFEAT; ++y) {
    float4 cc0 = pf0, cc1 = pf1;
    if (y + 1 < TFEAT) {   // depth-1 prefetch of next row
      pf0 = *(const float4*)(nb + (size_t)(y + 1) * TTXT);
      pf1 = *(const float4*)(nb + (size_t)(y + 1) * TTXT + 4);
    }
    float nf[8] = {cc0.x, cc0.y, cc0.z, cc0.w, cc1.x, cc1.y, cc1.z, cc1.w};
    float up = __shfl_up(prev[7], 1);
    bool my = (y < TTXT);

    // decision bits (based on prev = values[y-1], raw)
    unsigned int byte = 0;
    {
      unsigned int bit = (prev[0] < up) ? 1u : 0u;
      if (my && xbase == y) bit = 1u;
      if (lane == 0) bit = 0u;              // x == 0
      byte |= bit;
    }
    #pragma unroll
    for (int j = 1; j < 8; ++j) {
      unsigned int bit = (prev[j] < prev[j - 1]) ? 1u : 0u;
      if (my && (xbase + j) == y) bit = 1u;
      byte |= bit << j;
    }

    // value update: val = max(where(x==y, -inf, prev[x]), prev[x-1]) + neg
    float vleft0 = (lane == 0) ? ((y == 0) ? 0.0f : NEGINF) : up;
    float nv[8];
    {
      float vc = (my && xbase == y) ? NEGINF : prev[0];
      nv[0] = fmaxf(vc, vleft0) + nf[0];
    }
    #pragma unroll
    for (int j = 1; j < 8; ++j) {
      float vc = (my && (xbase + j) == y) ? NEGINF : prev[j];
      nv[j] = fmaxf(vc, prev[j - 1]) + nf[j];
    }
    #pragma unroll
    for (int j = 0; j < 8; ++j) prev[j] = nv[j];

    packed |= byte << ((y & 3) * 8);
    if ((y & 3) == 3) { bits[y >> 2][lane] = packed; packed = 0; }
  }
  __syncthreads();

  // backtrack (wave-uniform serial chain); dur = run lengths
  int idx = TTXT - 1;
  int cnt = 0;
  const float* xm = x_mask + (size_t)b * TTXT;
  for (int y = TFEAT - 1; y >= 0; --y) {
    if (lane == 0) idx_out[b * TFEAT + y] = idx;
    cnt++;
    unsigned int w = bits[y >> 2][idx >> 3];
    unsigned int bit = (w >> ((y & 3) * 8 + (idx & 7))) & 1u;
    if (bit) {
      if (lane == 0) dur[b * TTXT + idx] = (float)cnt * xm[idx];
      cnt = 0;
      idx--;
    }
  }
  if (lane == 0) dur[b * TTXT] = (float)cnt * xm[0];   // idx == 0 tail run
}

// ---------------------------------------------------------------------------
// Kernel D: attn[b,y,x] = (x == idx[y]) * x_mask[b,x] * y_mask[b,y]
// Full-grid float4 writes (must rewrite everything each call: out is poisoned).
// ---------------------------------------------------------------------------
__global__ void k_attn(const int* __restrict__ idx_arr,
                       const float* __restrict__ x_mask,
                       const float* __restrict__ y_mask,
                       float* __restrict__ attn) {
  size_t gid = (size_t)blockIdx.x * 256 + threadIdx.x;
  size_t e = gid << 2;               // 4 floats per thread
  int b = (int)(e >> 20);            // TFEAT*TTXT = 2^20
  int rem = (int)(e & 1048575u);
  int y = rem >> 9;
  int x0 = rem & 511;
  int idx = idx_arr[b * TFEAT + y];
  float4 v = {0.f, 0.f, 0.f, 0.f};
  int d = idx - x0;
  if (d >= 0 && d < 4) {
    ((float*)&v)[d] = x_mask[b * TTXT + idx] * y_mask[b * TFEAT + y];
  }
  *(float4*)(attn + e) = v;
}

// ---------------------------------------------------------------------------
extern "C" void kernel_launch(void* const* d_in, const int* in_sizes, int n_in,
                              void* d_out, int out_size, void* d_ws, size_t ws_size,
                              hipStream_t stream) {
  const float* z_p    = (const float*)d_in[0];
  const float* m_p    = (const float*)d_in[1];
  const float* logs_p = (const float*)d_in[2];
  const float* x_mask = (const float*)d_in[3];
  const float* y_mask = (const float*)d_in[4];

  float* out  = (float*)d_out;
  float* attn = out;
  float* dur  = out + DUR_OFF;
  float* neg  = out + NEG_OFF;

  // workspace: cadd (64 KiB) + idx array (256 KiB)
  float* cadd = (float*)d_ws;
  int*   idxa = (int*)((char*)d_ws + 65536);

  k_cadd<<<(BATCH * TTXT) / 256, 256, 0, stream>>>(m_p, logs_p, cadd);
  k_gemm<<<BATCH * (TFEAT / BM) * (TTXT / BN), 256, 0, stream>>>(z_p, m_p, logs_p, cadd, neg);
  k_dp<<<BATCH, 64, 0, stream>>>(neg, dur, idxa, x_mask);
  k_attn<<<(int)(ATTN_ELEMS / 4 / 256), 256, 0, stream>>>(idxa, x_mask, y_mask, attn);
}

// Round 2
// 1601.693 us; speedup vs baseline: 1.3849x; 1.3849x over previous
//
#include <hip/hip_runtime.h>
#include <math.h>

// Problem constants (fixed by the reference setup_inputs)
#define BATCH 32
#define CH    192
#define TFEAT 2048
#define TTXT  512
#define NEGINF (-1e9f)

#define ATTN_ELEMS ((size_t)BATCH * TFEAT * TTXT)   // 33,554,432
#define DUR_OFF    ATTN_ELEMS
#define NEG_OFF    (ATTN_ELEMS + (size_t)BATCH * TTXT)

// ---------------------------------------------------------------------------
// Kernel P: W1[b,c,s] = m*exp(-2*logs), W2[b,c,s] = -0.5*exp(-2*logs)
// Written into the attn region of d_out (fully rewritten later by k_attn).
// ---------------------------------------------------------------------------
__global__ void k_prep(const float* __restrict__ m_p,
                       const float* __restrict__ logs_p,
                       float* __restrict__ w1, float* __restrict__ w2) {
  int gid = blockIdx.x * 256 + threadIdx.x;    // 0 .. 3,145,727
  float m = m_p[gid];
  float l = logs_p[gid];
  float r = __expf(-2.0f * l);
  w1[gid] = m * r;
  w2[gid] = -0.5f * r;
}

// ---------------------------------------------------------------------------
// Kernel A: cadd[b][s] = sum_c(-0.5*log(2pi) - logs) + sum_c(-0.5*m^2*r)
// ---------------------------------------------------------------------------
__global__ void k_cadd(const float* __restrict__ m_p,
                       const float* __restrict__ logs_p,
                       float* __restrict__ cadd) {
  int gid = blockIdx.x * 256 + threadIdx.x;        // 0 .. 16383
  int b = gid >> 9, s = gid & (TTXT - 1);
  const float* mp = m_p    + (size_t)b * CH * TTXT + s;
  const float* lp = logs_p + (size_t)b * CH * TTXT + s;
  float acc = -0.5f * 1.8378770664093453f * (float)CH;   // -C/2 * log(2*pi)
  #pragma unroll 4
  for (int c = 0; c < CH; ++c) {
    float l = lp[(size_t)c * TTXT];
    float m = mp[(size_t)c * TTXT];
    float r = __expf(-2.0f * l);
    acc -= l + 0.5f * m * m * r;
  }
  cadd[gid] = acc;
}

// ---------------------------------------------------------------------------
// Kernel B: neg[b,t,s] = sum_c z*(W1 + z*W2) + cadd[b,s]
// fp32 vector GEMM. Tiles staged via global_load_lds (no staging registers,
// async DMA). B-fragment split into cols {tx*4, 64+tx*4} -> conflict-free.
// ---------------------------------------------------------------------------
#define BM 128
#define BN 128
#define BK 16

__device__ __forceinline__ void gload_lds16(const float* g, float* l) {
  __builtin_amdgcn_global_load_lds(
      (const __attribute__((address_space(1))) void*)g,
      (__attribute__((address_space(3))) void*)l, 16, 0, 0);
}

__global__ __launch_bounds__(256, 2)
void k_gemm(const float* __restrict__ z_p,
            const float* __restrict__ w1g, const float* __restrict__ w2g,
            const float* __restrict__ cadd, float* __restrict__ neg) {
  __shared__ float Az[BK][BM];
  __shared__ float B1[BK][BN];
  __shared__ float B2[BK][BN];

  int blk = blockIdx.x;
  int sb = blk & 3;            // TTXT/BN = 4
  int tb = (blk >> 2) & 15;    // TFEAT/BM = 16
  int b  = blk >> 6;
  int tid = threadIdx.x;
  int tx = tid & 15, ty = tid >> 4;        // 16 x 16 thread grid
  int wid  = tid >> 6;                     // wave 0..3
  int lane = tid & 63;
  int lr = lane >> 5;                      // row-within-pair
  int lc = (lane & 31) * 4;                // col (float4 granularity)

  const float* zb  = z_p + (size_t)b * CH * TFEAT + (size_t)tb * BM;
  const float* w1b = w1g + (size_t)b * CH * TTXT  + (size_t)sb * BN;
  const float* w2b = w2g + (size_t)b * CH * TTXT  + (size_t)sb * BN;

  float acc[8][8];
  #pragma unroll
  for (int i = 0; i < 8; ++i)
    #pragma unroll
    for (int j = 0; j < 8; ++j) acc[i][j] = 0.0f;

  for (int ko = 0; ko < CH / BK; ++ko) {
    int k0 = ko * BK;
    // stage 3 tiles: wave wid covers k-rows [wid*4, wid*4+4)
    #pragma unroll
    for (int i = 0; i < 2; ++i) {
      int kr = wid * 4 + i * 2 + lr;       // per-lane global k-row
      int kd = wid * 4 + i * 2;            // wave-uniform LDS row base
      gload_lds16(zb  + (size_t)(k0 + kr) * TFEAT + lc, &Az[kd][0]);
      gload_lds16(w1b + (size_t)(k0 + kr) * TTXT  + lc, &B1[kd][0]);
      gload_lds16(w2b + (size_t)(k0 + kr) * TTXT  + lc, &B2[kd][0]);
    }
    __syncthreads();                       // drains vmcnt (loads landed)

    #pragma unroll
    for (int kk = 0; kk < BK; ++kk) {
      float4 a0 = *(const float4*)&Az[kk][ty * 8];
      float4 a1 = *(const float4*)&Az[kk][ty * 8 + 4];
      float4 p0 = *(const float4*)&B1[kk][tx * 4];
      float4 p1 = *(const float4*)&B1[kk][64 + tx * 4];
      float4 q0 = *(const float4*)&B2[kk][tx * 4];
      float4 q1 = *(const float4*)&B2[kk][64 + tx * 4];
      float a[8]  = {a0.x, a0.y, a0.z, a0.w, a1.x, a1.y, a1.z, a1.w};
      float w1v[8] = {p0.x, p0.y, p0.z, p0.w, p1.x, p1.y, p1.z, p1.w};
      float w2v[8] = {q0.x, q0.y, q0.z, q0.w, q1.x, q1.y, q1.z, q1.w};
      #pragma unroll
      for (int i = 0; i < 8; ++i)
        #pragma unroll
        for (int j = 0; j < 8; ++j)
          acc[i][j] = fmaf(a[i], fmaf(a[i], w2v[j], w1v[j]), acc[i][j]);
    }
    __syncthreads();                       // tile consumed before restage
  }

  // epilogue: + cadd, store. cols: tx*4+jj and 64+tx*4+jj; rows: ty*8+i
  const float* cb = cadd + b * TTXT + sb * BN;
  float c0[4], c1[4];
  #pragma unroll
  for (int j = 0; j < 4; ++j) { c0[j] = cb[tx * 4 + j]; c1[j] = cb[64 + tx * 4 + j]; }
  float* ob = neg + (size_t)b * TFEAT * TTXT + (size_t)(tb * BM + ty * 8) * TTXT + sb * BN;
  #pragma unroll
  for (int i = 0; i < 8; ++i) {
    float4 o0 = {acc[i][0] + c0[0], acc[i][1] + c0[1], acc[i][2] + c0[2], acc[i][3] + c0[3]};
    float4 o1 = {acc[i][4] + c1[0], acc[i][5] + c1[1], acc[i][6] + c1[2], acc[i][7] + c1[3]};
    float* row = ob + (size_t)i * TTXT;
    *(float4*)(row + tx * 4)      = o0;
    *(float4*)(row + 64 + tx * 4) = o1;
  }
}

// ---------------------------------------------------------------------------
// Kernel C: forward DP (8-row register-double-buffered prefetch) + decision
// bits in LDS + windowed backtrack (2 current + 3 speculative words / 4 rows).
// One wave per batch element, x = 8*lane + j.
// ---------------------------------------------------------------------------
__device__ __forceinline__ void load8(float (&R)[8][8], const float* nb, int y0) {
  #pragma unroll
  for (int r = 0; r < 8; ++r) {
    float4 u = *(const float4*)(nb + (size_t)(y0 + r) * TTXT);
    float4 v = *(const float4*)(nb + (size_t)(y0 + r) * TTXT + 4);
    R[r][0] = u.x; R[r][1] = u.y; R[r][2] = u.z; R[r][3] = u.w;
    R[r][4] = v.x; R[r][5] = v.y; R[r][6] = v.z; R[r][7] = v.w;
  }
}

template<bool MASKED>
__device__ __forceinline__ void dp_rows8(float (&prev)[8], const float (&R)[8][8],
                                         int y0, int xbase, int lane,
                                         unsigned (*bits)[64]) {
  unsigned packed = 0;
  #pragma unroll
  for (int r = 0; r < 8; ++r) {
    int y = y0 + r;
    float up = __shfl_up(prev[7], 1);
    // decision bits (prev = values[y-1]): bit = (x!=0)&((x==y)|(prev[x]<prev[x-1]))
    unsigned byte;
    {
      unsigned bit = (prev[0] < up) ? 1u : 0u;
      if (MASKED && xbase == y) bit = 1u;
      if (lane == 0) bit = 0u;
      byte = bit;
    }
    #pragma unroll
    for (int j = 1; j < 8; ++j) {
      unsigned bit = (prev[j] < prev[j - 1]) ? 1u : 0u;
      if (MASKED && (xbase + j) == y) bit = 1u;
      byte |= bit << j;
    }
    // value update
    float vleft0;
    if (MASKED) vleft0 = (lane == 0) ? ((y == 0) ? 0.0f : NEGINF) : up;
    else        vleft0 = (lane == 0) ? NEGINF : up;
    float nv[8];
    {
      float vc = (MASKED && xbase == y) ? NEGINF : prev[0];
      nv[0] = fmaxf(vc, vleft0) + R[r][0];
    }
    #pragma unroll
    for (int j = 1; j < 8; ++j) {
      float vc = (MASKED && (xbase + j) == y) ? NEGINF : prev[j];
      nv[j] = fmaxf(vc, prev[j - 1]) + R[r][j];
    }
    #pragma unroll
    for (int j = 0; j < 8; ++j) prev[j] = nv[j];
    packed |= byte << ((r & 3) * 8);
    if ((r & 3) == 3) { bits[(y0 >> 2) + (r >> 2)][lane] = packed; packed = 0; }
  }
}

__global__ __launch_bounds__(64)
void k_dp(const float* __restrict__ neg, float* __restrict__ dur,
          int* __restrict__ idx_out, const float* __restrict__ x_mask) {
  __shared__ unsigned bits[TFEAT / 4][64];   // 128 KiB
  int b = blockIdx.x;
  int lane = threadIdx.x;
  const float* nb = neg + (size_t)b * TFEAT * TTXT + lane * 8;
  int xbase = lane * 8;

  float prev[8];
  #pragma unroll
  for (int j = 0; j < 8; ++j) prev[j] = NEGINF;

  float A[8][8], B[8][8];
  load8(A, nb, 0);
  load8(B, nb, 8);

  int y0 = 0;
  // masked region (y < TTXT): x==y forcing + y==0 boundary
  for (; y0 < TTXT; y0 += 16) {
    dp_rows8<true>(prev, A, y0, xbase, lane, bits);
    load8(A, nb, y0 + 16);
    dp_rows8<true>(prev, B, y0 + 8, xbase, lane, bits);
    load8(B, nb, y0 + 24);
  }
  // light region (y >= TTXT)
  for (; y0 < TFEAT; y0 += 16) {
    dp_rows8<false>(prev, A, y0, xbase, lane, bits);
    if (y0 + 16 < TFEAT) load8(A, nb, y0 + 16);
    dp_rows8<false>(prev, B, y0 + 8, xbase, lane, bits);
    if (y0 + 24 < TFEAT) load8(B, nb, y0 + 24);
  }
  __syncthreads();

  // ---- windowed backtrack: per yq (4 rows), hold words (xq0, xq0-1) in regs,
  // speculatively prefetch 3 words of the next yq (idx moves <= 4 per window).
  const float* xm = x_mask + (size_t)b * TTXT;
  int idx = TTXT - 1, cnt = 0;
  int xq0 = (TTXT - 1) >> 3;
  unsigned c0 = bits[TFEAT / 4 - 1][xq0];
  unsigned c1 = bits[TFEAT / 4 - 1][xq0 - 1];
  for (int yq = TFEAT / 4 - 1; yq >= 0; --yq) {
    unsigned n0 = 0, n1 = 0, n2 = 0;
    if (yq > 0) {
      int i1 = xq0 - 1 > 0 ? xq0 - 1 : 0;
      int i2 = xq0 - 2 > 0 ? xq0 - 2 : 0;
      n0 = bits[yq - 1][xq0];
      n1 = bits[yq - 1][i1];
      n2 = bits[yq - 1][i2];
    }
    #pragma unroll
    for (int r = 3; r >= 0; --r) {
      int y = yq * 4 + r;
      if (lane == 0) idx_out[b * TFEAT + y] = idx;
      cnt++;
      unsigned w = ((idx >> 3) == xq0) ? c0 : c1;
      unsigned bit = (w >> (r * 8 + (idx & 7))) & 1u;
      if (bit) {
        if (lane == 0) dur[b * TTXT + idx] = (float)cnt * xm[idx];
        cnt = 0;
        idx--;
      }
    }
    int nxq = idx >> 3;
    c0 = (nxq == xq0) ? n0 : n1;
    c1 = (nxq == xq0) ? n1 : n2;
    xq0 = nxq;
  }
  if (lane == 0) dur[b * TTXT] = (float)cnt * xm[0];   // idx == 0 tail run
}

// ---------------------------------------------------------------------------
// Kernel D: attn[b,y,x] = (x == idx[y]) * x_mask[b,x] * y_mask[b,y]
// ---------------------------------------------------------------------------
__global__ void k_attn(const int* __restrict__ idx_arr,
                       const float* __restrict__ x_mask,
                       const float* __restrict__ y_mask,
                       float* __restrict__ attn) {
  size_t gid = (size_t)blockIdx.x * 256 + threadIdx.x;
  size_t e = gid << 2;               // 4 floats per thread
  int b = (int)(e >> 20);            // TFEAT*TTXT = 2^20
  int rem = (int)(e & 1048575u);
  int y = rem >> 9;
  int x0 = rem & 511;
  int idx = idx_arr[b * TFEAT + y];
  float4 v = {0.f, 0.f, 0.f, 0.f};
  int d = idx - x0;
  if (d >= 0 && d < 4) {
    ((float*)&v)[d] = x_mask[b * TTXT + idx] * y_mask[b * TFEAT + y];
  }
  *(float4*)(attn + e) = v;
}

// ---------------------------------------------------------------------------
extern "C" void kernel_launch(void* const* d_in, const int* in_sizes, int n_in,
                              void* d_out, int out_size, void* d_ws, size_t ws_size,
                              hipStream_t stream) {
  const float* z_p    = (const float*)d_in[0];
  const float* m_p    = (const float*)d_in[1];
  const float* logs_p = (const float*)d_in[2];
  const float* x_mask = (const float*)d_in[3];
  const float* y_mask = (const float*)d_in[4];

  float* out  = (float*)d_out;
  float* attn = out;
  float* dur  = out + DUR_OFF;
  float* neg  = out + NEG_OFF;

  // W1/W2 scratch lives in the attn region (fully rewritten by k_attn later)
  float* w1s = attn;
  float* w2s = attn + (size_t)BATCH * CH * TTXT;      // 3,145,728 floats each

  // workspace: cadd (64 KiB) + idx array (256 KiB)
  float* cadd = (float*)d_ws;
  int*   idxa = (int*)((char*)d_ws + 65536);

  k_prep<<<(BATCH * CH * TTXT) / 256, 256, 0, stream>>>(m_p, logs_p, w1s, w2s);
  k_cadd<<<(BATCH * TTXT) / 256, 256, 0, stream>>>(m_p, logs_p, cadd);
  k_gemm<<<BATCH * (TFEAT / BM) * (TTXT / BN), 256, 0, stream>>>(z_p, w1s, w2s, cadd, neg);
  k_dp<<<BATCH, 64, 0, stream>>>(neg, dur, idxa, x_mask);
  k_attn<<<(int)(ATTN_ELEMS / 4 / 256), 256, 0, stream>>>(idxa, x_mask, y_mask, attn);
}